// Round 3
// baseline (223.531 us; speedup 1.0000x reference)
//
#include <hip/hip_runtime.h>
#include <math.h>

#define NODE_D 128
#define HID 16

// round-to-nearest-even float -> bf16, packed pairwise
__device__ __forceinline__ unsigned pack2bf16(float a, float b) {
    unsigned ua = __float_as_uint(a);
    ua = (ua + 0x7fffu + ((ua >> 16) & 1u)) >> 16;
    unsigned ub = __float_as_uint(b);
    ub = (ub + 0x7fffu + ((ub >> 16) & 1u)) >> 16;
    return ua | (ub << 16);
}

// ---------------------------------------------------------------------------
// Kernel 1: per-node. U = z @ W1[:128] + b1, V = z @ W1[128:].
// One node/thread. Loads batched 8-deep per group for memory-level
// parallelism (the round-2 version had 1 load in flight -> latency-bound at
// 2 TB/s). W1 addresses are compile-time/wave-uniform -> s_load (scalar
// cache), no LDS. Also emits a bf16 copy of z as uint4 stores.
// ---------------------------------------------------------------------------
__global__ __launch_bounds__(256) void precompute_kernel(
    const float* __restrict__ z, const float* __restrict__ W1,
    const float* __restrict__ b1,
    float* __restrict__ U, float* __restrict__ V,
    uint4* __restrict__ zh, int n_nodes, int write_zh)
{
    const int node = blockIdx.x * 256 + threadIdx.x;
    if (node >= n_nodes) return;

    const float4* zp   = (const float4*)(z + (size_t)node * NODE_D);
    uint4*        zh4p = zh + (size_t)node * (NODE_D / 8);

    float u[HID], v[HID];
    #pragma unroll
    for (int j = 0; j < HID; ++j) { u[j] = b1[j]; v[j] = 0.f; }

    #pragma unroll
    for (int g = 0; g < 4; ++g) {
        float4 za[8];
        #pragma unroll
        for (int k = 0; k < 8; ++k) za[k] = zp[g * 8 + k];   // 8 loads in flight

        if (write_zh) {
            #pragma unroll
            for (int k = 0; k < 8; k += 2) {
                uint4 pk;
                pk.x = pack2bf16(za[k].x,   za[k].y);
                pk.y = pack2bf16(za[k].z,   za[k].w);
                pk.z = pack2bf16(za[k+1].x, za[k+1].y);
                pk.w = pack2bf16(za[k+1].z, za[k+1].w);
                zh4p[g * 4 + k / 2] = pk;
            }
        }

        #pragma unroll
        for (int k = 0; k < 8; ++k) {
            const int c = g * 8 + k;
            const float* wu = W1 + (size_t)c * 4 * HID;   // rows 4c..4c+3
            const float* wv = wu + NODE_D * HID;          // rows 128+4c..
            #pragma unroll
            for (int j = 0; j < HID; ++j) {
                u[j] = fmaf(za[k].x, wu[j],
                       fmaf(za[k].y, wu[HID + j],
                       fmaf(za[k].z, wu[2 * HID + j],
                       fmaf(za[k].w, wu[3 * HID + j], u[j]))));
                v[j] = fmaf(za[k].x, wv[j],
                       fmaf(za[k].y, wv[HID + j],
                       fmaf(za[k].z, wv[2 * HID + j],
                       fmaf(za[k].w, wv[3 * HID + j], v[j]))));
            }
        }
    }

    float4* up = (float4*)(U + (size_t)node * HID);
    float4* vp = (float4*)(V + (size_t)node * HID);
    #pragma unroll
    for (int q = 0; q < 4; ++q) {
        up[q] = make_float4(u[4*q], u[4*q+1], u[4*q+2], u[4*q+3]);
        vp[q] = make_float4(v[4*q], v[4*q+1], v[4*q+2], v[4*q+3]);
    }
}

// ---------------------------------------------------------------------------
// Kernel 2 (bf16 dot path): 8 lanes/edge. Lane l loads 32 B of each row
// (2x uint4), giving 4 gather loads in flight per thread; U/V/W2 read as
// float2 (lane l handles hidden units 2l, 2l+1). Reduction depth 3.
// ---------------------------------------------------------------------------
__global__ __launch_bounds__(256) void edge_kernel_bf16(
    const uint4* __restrict__ zh, const int* __restrict__ ei,
    const float* __restrict__ U, const float* __restrict__ V,
    const float* __restrict__ W2, const float* __restrict__ b2,
    float* __restrict__ out, int E)
{
    const int gid  = blockIdx.x * blockDim.x + threadIdx.x;
    const int eid  = gid >> 3;
    const int lane = threadIdx.x & 7;
    if (eid >= E) return;

    const int row = ei[eid];
    const int col = ei[E + eid];

    const size_t rb = (size_t)row * (NODE_D / 8);   // 16 uint4 per row
    const size_t cb = (size_t)col * (NODE_D / 8);
    uint4 ra0 = zh[rb + 2 * lane];
    uint4 ra1 = zh[rb + 2 * lane + 1];
    uint4 rc0 = zh[cb + 2 * lane];
    uint4 rc1 = zh[cb + 2 * lane + 1];

    const float2* U2  = (const float2*)U;
    const float2* V2  = (const float2*)V;
    const float2* W22 = (const float2*)W2;
    float2 ur = U2[(size_t)row * (HID / 2) + lane];
    float2 vc = V2[(size_t)col * (HID / 2) + lane];
    float2 w2 = W22[lane];

    float p = 0.f;
    {
        const unsigned* au = (const unsigned*)&ra0;
        const unsigned* cu = (const unsigned*)&rc0;
        #pragma unroll
        for (int q = 0; q < 4; ++q) {
            p = fmaf(__uint_as_float(au[q] << 16),        __uint_as_float(cu[q] << 16), p);
            p = fmaf(__uint_as_float(au[q] & 0xffff0000u),__uint_as_float(cu[q] & 0xffff0000u), p);
        }
        au = (const unsigned*)&ra1;
        cu = (const unsigned*)&rc1;
        #pragma unroll
        for (int q = 0; q < 4; ++q) {
            p = fmaf(__uint_as_float(au[q] << 16),        __uint_as_float(cu[q] << 16), p);
            p = fmaf(__uint_as_float(au[q] & 0xffff0000u),__uint_as_float(cu[q] & 0xffff0000u), p);
        }
    }
    p += __shfl_xor(p, 1);
    p += __shfl_xor(p, 2);
    p += __shfl_xor(p, 4);

    float t = fmaxf(ur.x + vc.x, 0.f) * w2.x + fmaxf(ur.y + vc.y, 0.f) * w2.y;
    t += __shfl_xor(t, 1);
    t += __shfl_xor(t, 2);
    t += __shfl_xor(t, 4);

    if (lane == 0) {
        float x = t + b2[0];
        float w = fmaxf(x, 0.f) + log1pf(expf(-fabsf(x)));
        out[eid]     = p;
        out[E + eid] = w;
    }
}

// ---------------------------------------------------------------------------
// Kernel 2 (fp32 fallback, used only if d_ws can't hold the bf16 z copy)
// ---------------------------------------------------------------------------
__global__ __launch_bounds__(256) void edge_kernel_f32(
    const float* __restrict__ z, const int* __restrict__ ei,
    const float* __restrict__ U, const float* __restrict__ V,
    const float* __restrict__ W2, const float* __restrict__ b2,
    float* __restrict__ out, int E)
{
    const int gid  = blockIdx.x * blockDim.x + threadIdx.x;
    const int eid  = gid >> 4;
    const int lane = threadIdx.x & 15;
    if (eid >= E) return;

    const int row = ei[eid];
    const int col = ei[E + eid];

    const float4* zr = (const float4*)(z + (size_t)row * NODE_D);
    const float4* zc = (const float4*)(z + (size_t)col * NODE_D);
    float4 a0 = zr[lane], a1 = zr[lane + 16];
    float4 c0 = zc[lane], c1 = zc[lane + 16];

    float p = a0.x*c0.x + a0.y*c0.y + a0.z*c0.z + a0.w*c0.w
            + a1.x*c1.x + a1.y*c1.y + a1.z*c1.z + a1.w*c1.w;
    p += __shfl_xor(p, 1);
    p += __shfl_xor(p, 2);
    p += __shfl_xor(p, 4);
    p += __shfl_xor(p, 8);

    float hu = U[(size_t)row * HID + lane] + V[(size_t)col * HID + lane];
    float t  = fmaxf(hu, 0.f) * W2[lane];
    t += __shfl_xor(t, 1);
    t += __shfl_xor(t, 2);
    t += __shfl_xor(t, 4);
    t += __shfl_xor(t, 8);

    if (lane == 0) {
        float x = t + b2[0];
        float w = fmaxf(x, 0.f) + log1pf(expf(-fabsf(x)));
        out[eid]     = p;
        out[E + eid] = w;
    }
}

extern "C" void kernel_launch(void* const* d_in, const int* in_sizes, int n_in,
                              void* d_out, int out_size, void* d_ws, size_t ws_size,
                              hipStream_t stream) {
    const float* z  = (const float*)d_in[0];
    const int*   ei = (const int*)  d_in[1];
    const float* W1 = (const float*)d_in[2];
    const float* b1 = (const float*)d_in[3];
    const float* W2 = (const float*)d_in[4];
    const float* b2 = (const float*)d_in[5];
    float* out = (float*)d_out;

    const int n_nodes = in_sizes[0] / NODE_D;   // 100000
    const int E       = in_sizes[1] / 2;        // 600000

    const size_t needUV = (size_t)2 * n_nodes * HID * sizeof(float);  // 12.8 MB
    const size_t needZh = (size_t)n_nodes * NODE_D * 2;               // 25.6 MB
    const int use_bf16  = (ws_size >= needUV + needZh);

    float* U  = (float*)d_ws;
    float* V  = U + (size_t)n_nodes * HID;
    uint4* zh = (uint4*)((char*)d_ws + needUV);

    precompute_kernel<<<(n_nodes + 255) / 256, 256, 0, stream>>>(
        z, W1, b1, U, V, zh, n_nodes, use_bf16);

    if (use_bf16) {
        const long long threads = (long long)E * 8;
        edge_kernel_bf16<<<(unsigned)((threads + 255) / 256), 256, 0, stream>>>(
            zh, ei, U, V, W2, b2, out, E);
    } else {
        const long long threads = (long long)E * 16;
        edge_kernel_f32<<<(unsigned)((threads + 255) / 256), 256, 0, stream>>>(
            z, ei, U, V, W2, b2, out, E);
    }
}

// Round 4
// 165.783 us; speedup vs baseline: 1.3483x; 1.3483x over previous
//
#include <hip/hip_runtime.h>
#include <math.h>

#define NODE_D 128
#define HID 16

typedef __attribute__((ext_vector_type(8))) short bf16x8_t;   // 8 bf16 (4 VGPRs)
typedef __attribute__((ext_vector_type(4))) float f32x4_t;    // MFMA acc

// round-to-nearest-even float -> bf16
__device__ __forceinline__ unsigned short bf16rne(float x) {
    unsigned u = __float_as_uint(x);
    u = (u + 0x7fffu + ((u >> 16) & 1u)) >> 16;
    return (unsigned short)u;
}

// ---------------------------------------------------------------------------
// Kernel 1 (MFMA): U = z@W1[:128] + b1, V = z@W1[128:], plus bf16 z copy.
// One wave = 16 nodes x 32 outputs = 8 MFMAs; W1 fragments register-resident
// (the R2/R3 versions died on s_load W1 operand chains at 16% occupancy).
// A-fragment loads double as the z->bf16 conversion pass (z read once).
// A layout: A[m=lane&15][k=(lane>>4)*8+j]; C/D: col=lane&15, row=quad*4+reg.
// ---------------------------------------------------------------------------
__global__ __launch_bounds__(256) void precompute_mfma(
    const float* __restrict__ z, const float* __restrict__ W1,
    const float* __restrict__ b1,
    float* __restrict__ U, float* __restrict__ V,
    uint4* __restrict__ zh, int n_nodes)
{
    const int tid   = threadIdx.x;
    const int wave  = tid >> 6;
    const int lane  = tid & 63;
    const int m     = lane & 15;
    const int quad  = lane >> 4;
    const int nbase = blockIdx.x * 64 + wave * 16;
    const int node  = nbase + m;
    const int nodec = node < n_nodes ? node : (n_nodes - 1);

    // ---- B fragments from W1 (rows 0..127 -> U, rows 128..255 -> V) ----
    // B[k][n]: n = lane&15, k = quad*8 + jj (+ 32*s per step)
    bf16x8_t bU[4], bV[4];
    #pragma unroll
    for (int s = 0; s < 4; ++s) {
        union { bf16x8_t v; unsigned short u[8]; } tu, tv;
        #pragma unroll
        for (int jj = 0; jj < 8; ++jj) {
            const int k = s * 32 + quad * 8 + jj;
            tu.u[jj] = bf16rne(W1[k * HID + m]);
            tv.u[jj] = bf16rne(W1[(NODE_D + k) * HID + m]);
        }
        bU[s] = tu.v;
        bV[s] = tv.v;
    }

    // ---- A fragments from z (+ write bf16 copy to zh) ----
    bf16x8_t a[4];
    const float4* zrow = (const float4*)(z + (size_t)nodec * NODE_D);
    #pragma unroll
    for (int s = 0; s < 4; ++s) {
        float4 f0 = zrow[s * 8 + quad * 2];
        float4 f1 = zrow[s * 8 + quad * 2 + 1];
        union { bf16x8_t v; unsigned short u[8]; uint4 q; } ta;
        ta.u[0] = bf16rne(f0.x); ta.u[1] = bf16rne(f0.y);
        ta.u[2] = bf16rne(f0.z); ta.u[3] = bf16rne(f0.w);
        ta.u[4] = bf16rne(f1.x); ta.u[5] = bf16rne(f1.y);
        ta.u[6] = bf16rne(f1.z); ta.u[7] = bf16rne(f1.w);
        a[s] = ta.v;
        if (node < n_nodes)
            zh[(size_t)node * (NODE_D / 8) + s * 4 + quad] = ta.q;
    }

    // ---- MFMA: b1 folded into the U accumulator init ----
    const float bias = b1[m];
    f32x4_t accU = {bias, bias, bias, bias};
    f32x4_t accV = {0.f, 0.f, 0.f, 0.f};
    #pragma unroll
    for (int s = 0; s < 4; ++s) {
        accU = __builtin_amdgcn_mfma_f32_16x16x32_bf16(a[s], bU[s], accU, 0, 0, 0);
        accV = __builtin_amdgcn_mfma_f32_16x16x32_bf16(a[s], bV[s], accV, 0, 0, 0);
    }

    // ---- store: lane holds D[row=quad*4+r][col=lane&15] ----
    #pragma unroll
    for (int r = 0; r < 4; ++r) {
        const int nodeo = nbase + quad * 4 + r;
        if (nodeo < n_nodes) {
            U[(size_t)nodeo * HID + m] = accU[r];
            V[(size_t)nodeo * HID + m] = accV[r];
        }
    }
}

__device__ __forceinline__ float dot_bf16x8(uint4 a, uint4 c, float p) {
    const unsigned* au = (const unsigned*)&a;
    const unsigned* cu = (const unsigned*)&c;
    #pragma unroll
    for (int q = 0; q < 4; ++q) {
        p = fmaf(__uint_as_float(au[q] << 16),
                 __uint_as_float(cu[q] << 16), p);
        p = fmaf(__uint_as_float(au[q] & 0xffff0000u),
                 __uint_as_float(cu[q] & 0xffff0000u), p);
    }
    return p;
}

// ---------------------------------------------------------------------------
// Kernel 2: 16 lanes handle TWO edges (4 zh gathers + 4 U/V gathers in
// flight per thread -> 2x outstanding loads vs one-edge version; the edge
// pass is gather-latency-bound, not BW-bound).
// ---------------------------------------------------------------------------
__global__ __launch_bounds__(256) void edge_kernel_bf16(
    const uint4* __restrict__ zh, const int* __restrict__ ei,
    const float* __restrict__ U, const float* __restrict__ V,
    const float* __restrict__ W2, const float* __restrict__ b2,
    float* __restrict__ out, int E)
{
    const int gid  = blockIdx.x * 256 + threadIdx.x;
    const int g    = gid >> 4;          // edge-pair id
    const int lane = threadIdx.x & 15;
    const int e0   = 2 * g;
    if (e0 >= E) return;
    const bool has2 = (e0 + 1) < E;

    const int r0 = ei[e0];
    const int c0 = ei[E + e0];
    const int r1 = has2 ? ei[e0 + 1]     : r0;
    const int c1 = has2 ? ei[E + e0 + 1] : c0;

    uint4 za0 = zh[(size_t)r0 * (NODE_D / 8) + lane];
    uint4 zc0 = zh[(size_t)c0 * (NODE_D / 8) + lane];
    uint4 za1 = zh[(size_t)r1 * (NODE_D / 8) + lane];
    uint4 zc1 = zh[(size_t)c1 * (NODE_D / 8) + lane];

    float u0 = U[(size_t)r0 * HID + lane];
    float v0 = V[(size_t)c0 * HID + lane];
    float u1 = U[(size_t)r1 * HID + lane];
    float v1 = V[(size_t)c1 * HID + lane];
    float w2 = W2[lane];

    float p0 = dot_bf16x8(za0, zc0, 0.f);
    float p1 = dot_bf16x8(za1, zc1, 0.f);
    p0 += __shfl_xor(p0, 1); p1 += __shfl_xor(p1, 1);
    p0 += __shfl_xor(p0, 2); p1 += __shfl_xor(p1, 2);
    p0 += __shfl_xor(p0, 4); p1 += __shfl_xor(p1, 4);
    p0 += __shfl_xor(p0, 8); p1 += __shfl_xor(p1, 8);

    float t0 = fmaxf(u0 + v0, 0.f) * w2;   // b1 already folded into U
    float t1 = fmaxf(u1 + v1, 0.f) * w2;
    t0 += __shfl_xor(t0, 1); t1 += __shfl_xor(t1, 1);
    t0 += __shfl_xor(t0, 2); t1 += __shfl_xor(t1, 2);
    t0 += __shfl_xor(t0, 4); t1 += __shfl_xor(t1, 4);
    t0 += __shfl_xor(t0, 8); t1 += __shfl_xor(t1, 8);

    if (lane == 0) {
        const float bb = b2[0];
        float x0 = t0 + bb;
        float x1 = t1 + bb;
        float w0 = fmaxf(x0, 0.f) + log1pf(expf(-fabsf(x0)));
        float w1 = fmaxf(x1, 0.f) + log1pf(expf(-fabsf(x1)));
        if (has2) {
            *(float2*)(out + e0)     = make_float2(p0, p1);   // e0 even -> aligned
            *(float2*)(out + E + e0) = make_float2(w0, w1);   // E even
        } else {
            out[e0]     = p0;
            out[E + e0] = w0;
        }
    }
}

// ---------------------------------------------------------------------------
// Fallbacks (only if d_ws can't hold the bf16 z copy): scalar precompute +
// fp32 edge kernel.
// ---------------------------------------------------------------------------
__global__ __launch_bounds__(256) void precompute_scalar(
    const float* __restrict__ z, const float* __restrict__ W1,
    const float* __restrict__ b1,
    float* __restrict__ U, float* __restrict__ V, int n_nodes)
{
    const int node = blockIdx.x * 256 + threadIdx.x;
    if (node >= n_nodes) return;
    const float4* zp = (const float4*)(z + (size_t)node * NODE_D);
    float u[HID], v[HID];
    #pragma unroll
    for (int j = 0; j < HID; ++j) { u[j] = b1[j]; v[j] = 0.f; }
    #pragma unroll 1
    for (int c = 0; c < NODE_D / 4; ++c) {
        float4 za = zp[c];
        const float* wu = W1 + (size_t)c * 4 * HID;
        const float* wv = wu + NODE_D * HID;
        #pragma unroll
        for (int j = 0; j < HID; ++j) {
            u[j] = fmaf(za.x, wu[j], fmaf(za.y, wu[HID + j],
                   fmaf(za.z, wu[2 * HID + j], fmaf(za.w, wu[3 * HID + j], u[j]))));
            v[j] = fmaf(za.x, wv[j], fmaf(za.y, wv[HID + j],
                   fmaf(za.z, wv[2 * HID + j], fmaf(za.w, wv[3 * HID + j], v[j]))));
        }
    }
    float4* up = (float4*)(U + (size_t)node * HID);
    float4* vp = (float4*)(V + (size_t)node * HID);
    #pragma unroll
    for (int q = 0; q < 4; ++q) {
        up[q] = make_float4(u[4*q], u[4*q+1], u[4*q+2], u[4*q+3]);
        vp[q] = make_float4(v[4*q], v[4*q+1], v[4*q+2], v[4*q+3]);
    }
}

__global__ __launch_bounds__(256) void edge_kernel_f32(
    const float* __restrict__ z, const int* __restrict__ ei,
    const float* __restrict__ U, const float* __restrict__ V,
    const float* __restrict__ W2, const float* __restrict__ b2,
    float* __restrict__ out, int E)
{
    const int gid  = blockIdx.x * blockDim.x + threadIdx.x;
    const int eid  = gid >> 4;
    const int lane = threadIdx.x & 15;
    if (eid >= E) return;
    const int row = ei[eid];
    const int col = ei[E + eid];
    const float4* zr = (const float4*)(z + (size_t)row * NODE_D);
    const float4* zc = (const float4*)(z + (size_t)col * NODE_D);
    float4 a0 = zr[lane], a1 = zr[lane + 16];
    float4 c0 = zc[lane], c1 = zc[lane + 16];
    float p = a0.x*c0.x + a0.y*c0.y + a0.z*c0.z + a0.w*c0.w
            + a1.x*c1.x + a1.y*c1.y + a1.z*c1.z + a1.w*c1.w;
    p += __shfl_xor(p, 1); p += __shfl_xor(p, 2);
    p += __shfl_xor(p, 4); p += __shfl_xor(p, 8);
    float t = fmaxf(U[(size_t)row * HID + lane] + V[(size_t)col * HID + lane], 0.f) * W2[lane];
    t += __shfl_xor(t, 1); t += __shfl_xor(t, 2);
    t += __shfl_xor(t, 4); t += __shfl_xor(t, 8);
    if (lane == 0) {
        float x = t + b2[0];
        out[eid]     = p;
        out[E + eid] = fmaxf(x, 0.f) + log1pf(expf(-fabsf(x)));
    }
}

extern "C" void kernel_launch(void* const* d_in, const int* in_sizes, int n_in,
                              void* d_out, int out_size, void* d_ws, size_t ws_size,
                              hipStream_t stream) {
    const float* z  = (const float*)d_in[0];
    const int*   ei = (const int*)  d_in[1];
    const float* W1 = (const float*)d_in[2];
    const float* b1 = (const float*)d_in[3];
    const float* W2 = (const float*)d_in[4];
    const float* b2 = (const float*)d_in[5];
    float* out = (float*)d_out;

    const int n_nodes = in_sizes[0] / NODE_D;   // 100000
    const int E       = in_sizes[1] / 2;        // 600000

    const size_t needUV = (size_t)2 * n_nodes * HID * sizeof(float);  // 12.8 MB
    const size_t needZh = (size_t)n_nodes * NODE_D * 2;               // 25.6 MB
    const int use_bf16  = (ws_size >= needUV + needZh);

    float* U  = (float*)d_ws;
    float* V  = U + (size_t)n_nodes * HID;
    uint4* zh = (uint4*)((char*)d_ws + needUV);

    if (use_bf16) {
        precompute_mfma<<<(n_nodes + 63) / 64, 256, 0, stream>>>(
            z, W1, b1, U, V, zh, n_nodes);
        const long long groups  = ((long long)E + 1) / 2;
        const long long threads = groups * 16;
        edge_kernel_bf16<<<(unsigned)((threads + 255) / 256), 256, 0, stream>>>(
            zh, ei, U, V, W2, b2, out, E);
    } else {
        precompute_scalar<<<(n_nodes + 255) / 256, 256, 0, stream>>>(
            z, W1, b1, U, V, n_nodes);
        const long long threads = (long long)E * 16;
        edge_kernel_f32<<<(unsigned)((threads + 255) / 256), 256, 0, stream>>>(
            z, ei, U, V, W2, b2, out, E);
    }
}

// Round 5
// 164.926 us; speedup vs baseline: 1.3553x; 1.0052x over previous
//
#include <hip/hip_runtime.h>
#include <math.h>

#define NODE_D 128
#define HID 16

typedef _Float16 f16x8_t __attribute__((ext_vector_type(8)));   // 8 f16 (4 VGPRs)
typedef _Float16 f16x2_t __attribute__((ext_vector_type(2)));
typedef float    f32x4_t __attribute__((ext_vector_type(4)));   // MFMA acc

// ---------------------------------------------------------------------------
// Kernel 1 (MFMA f16): U = z@W1[:128] + b1, V = z@W1[128:], plus f16 z copy.
// W1 staged ONCE per block into LDS in fragment-transposed order (the R4
// version had every wave pull 16 KB of W1 through per-lane global loads —
// ~100 MB aggregate and 64-deep issue chains; that was the ~100 us hog).
// Per wave: 16 nodes x 32 outputs = 8 MFMAs; B-frags via one ds_read_b128.
// A layout: A[m=lane&15][k=quad*8+j (+32s)]; C/D: col=lane&15, row=quad*4+reg.
// ---------------------------------------------------------------------------
__global__ __launch_bounds__(256) void precompute_mfma(
    const float* __restrict__ z, const float* __restrict__ W1,
    const float* __restrict__ b1,
    float* __restrict__ U, float* __restrict__ V,
    uint4* __restrict__ zh, int n_nodes)
{
    // fragment-ordered W1: ldsU[((s*4+quad)*16 + m)*8 + jj] = W1[(32s+8q+jj)*16 + m]
    __shared__ _Float16 ldsU[4096];   // 8 KB
    __shared__ _Float16 ldsV[4096];   // 8 KB

    const int tid = threadIdx.x;
    #pragma unroll
    for (int i = 0; i < 32; ++i) {
        const int e = i * 256 + tid;          // coalesced over W1's 8192 floats
        const float val = W1[e];
        int k = e >> 4;
        const int m = e & 15;
        _Float16* dst = ldsU;
        if (k >= NODE_D) { k -= NODE_D; dst = ldsV; }
        const int s = k >> 5, q = (k >> 3) & 3, jj = k & 7;
        dst[(((s * 4 + q) * 16 + m) << 3) + jj] = (_Float16)val;
    }
    __syncthreads();

    const int wave  = tid >> 6;
    const int lane  = tid & 63;
    const int m     = lane & 15;
    const int quad  = lane >> 4;
    const int nbase = blockIdx.x * 64 + wave * 16;
    const int node  = nbase + m;
    const int nodec = node < n_nodes ? node : (n_nodes - 1);

    // ---- A fragments from z (+ write f16 copy to zh) ----
    f16x8_t a[4];
    const float4* zrow = (const float4*)(z + (size_t)nodec * NODE_D);
    #pragma unroll
    for (int s = 0; s < 4; ++s) {
        float4 f0 = zrow[s * 8 + quad * 2];
        float4 f1 = zrow[s * 8 + quad * 2 + 1];
        union { f16x8_t v; _Float16 h[8]; uint4 q4; } ta;
        ta.h[0] = (_Float16)f0.x; ta.h[1] = (_Float16)f0.y;
        ta.h[2] = (_Float16)f0.z; ta.h[3] = (_Float16)f0.w;
        ta.h[4] = (_Float16)f1.x; ta.h[5] = (_Float16)f1.y;
        ta.h[6] = (_Float16)f1.z; ta.h[7] = (_Float16)f1.w;
        a[s] = ta.v;
        if (node < n_nodes)
            zh[(size_t)node * (NODE_D / 8) + s * 4 + quad] = ta.q4;
    }

    // ---- B fragments from LDS (one ds_read_b128 each) ----
    const float bias = b1[m];
    f32x4_t accU = {bias, bias, bias, bias};
    f32x4_t accV = {0.f, 0.f, 0.f, 0.f};
    #pragma unroll
    for (int s = 0; s < 4; ++s) {
        f16x8_t bu = *(const f16x8_t*)(ldsU + (((s * 4 + quad) * 16 + m) << 3));
        f16x8_t bv = *(const f16x8_t*)(ldsV + (((s * 4 + quad) * 16 + m) << 3));
        accU = __builtin_amdgcn_mfma_f32_16x16x32_f16(a[s], bu, accU, 0, 0, 0);
        accV = __builtin_amdgcn_mfma_f32_16x16x32_f16(a[s], bv, accV, 0, 0, 0);
    }

    // ---- store: lane holds D[row=quad*4+r][col=m] ----
    #pragma unroll
    for (int r = 0; r < 4; ++r) {
        const int nodeo = nbase + quad * 4 + r;
        if (nodeo < n_nodes) {
            U[(size_t)nodeo * HID + m] = accU[r];
            V[(size_t)nodeo * HID + m] = accV[r];
        }
    }
}

// dot of 8 packed f16 pairs via v_dot2_f32_f16 (1 instr / 2 elements)
__device__ __forceinline__ float dot_f16x8(uint4 a, uint4 c, float p) {
    union { uint4 u; f16x2_t h[4]; } A, C;
    A.u = a; C.u = c;
#if __has_builtin(__builtin_amdgcn_fdot2)
    #pragma unroll
    for (int q = 0; q < 4; ++q)
        p = __builtin_amdgcn_fdot2(A.h[q], C.h[q], p, false);
#else
    #pragma unroll
    for (int q = 0; q < 4; ++q) {
        p = fmaf((float)A.h[q][0], (float)C.h[q][0], p);
        p = fmaf((float)A.h[q][1], (float)C.h[q][1], p);
    }
#endif
    return p;
}

// ---------------------------------------------------------------------------
// Kernel 2: 16 lanes handle TWO edges (4 zh gathers + 4 U/V gathers in
// flight per thread). f16 dot via fdot2 cuts dot VALU ~4x vs bf16 unpack.
// ---------------------------------------------------------------------------
__global__ __launch_bounds__(256) void edge_kernel_f16(
    const uint4* __restrict__ zh, const int* __restrict__ ei,
    const float* __restrict__ U, const float* __restrict__ V,
    const float* __restrict__ W2, const float* __restrict__ b2,
    float* __restrict__ out, int E)
{
    const int gid  = blockIdx.x * 256 + threadIdx.x;
    const int g    = gid >> 4;          // edge-pair id
    const int lane = threadIdx.x & 15;
    const int e0   = 2 * g;
    if (e0 >= E) return;
    const bool has2 = (e0 + 1) < E;

    const int r0 = ei[e0];
    const int c0 = ei[E + e0];
    const int r1 = has2 ? ei[e0 + 1]     : r0;
    const int c1 = has2 ? ei[E + e0 + 1] : c0;

    uint4 za0 = zh[(size_t)r0 * (NODE_D / 8) + lane];
    uint4 zc0 = zh[(size_t)c0 * (NODE_D / 8) + lane];
    uint4 za1 = zh[(size_t)r1 * (NODE_D / 8) + lane];
    uint4 zc1 = zh[(size_t)c1 * (NODE_D / 8) + lane];

    float u0 = U[(size_t)r0 * HID + lane];
    float v0 = V[(size_t)c0 * HID + lane];
    float u1 = U[(size_t)r1 * HID + lane];
    float v1 = V[(size_t)c1 * HID + lane];
    float w2 = W2[lane];

    float p0 = dot_f16x8(za0, zc0, 0.f);
    float p1 = dot_f16x8(za1, zc1, 0.f);
    p0 += __shfl_xor(p0, 1); p1 += __shfl_xor(p1, 1);
    p0 += __shfl_xor(p0, 2); p1 += __shfl_xor(p1, 2);
    p0 += __shfl_xor(p0, 4); p1 += __shfl_xor(p1, 4);
    p0 += __shfl_xor(p0, 8); p1 += __shfl_xor(p1, 8);

    float t0 = fmaxf(u0 + v0, 0.f) * w2;   // b1 already folded into U
    float t1 = fmaxf(u1 + v1, 0.f) * w2;
    t0 += __shfl_xor(t0, 1); t1 += __shfl_xor(t1, 1);
    t0 += __shfl_xor(t0, 2); t1 += __shfl_xor(t1, 2);
    t0 += __shfl_xor(t0, 4); t1 += __shfl_xor(t1, 4);
    t0 += __shfl_xor(t0, 8); t1 += __shfl_xor(t1, 8);

    if (lane == 0) {
        const float bb = b2[0];
        float x0 = t0 + bb;
        float x1 = t1 + bb;
        float w0 = fmaxf(x0, 0.f) + log1pf(expf(-fabsf(x0)));
        float w1 = fmaxf(x1, 0.f) + log1pf(expf(-fabsf(x1)));
        if (has2) {
            *(float2*)(out + e0)     = make_float2(p0, p1);   // e0 even -> aligned
            *(float2*)(out + E + e0) = make_float2(w0, w1);   // E even
        } else {
            out[e0]     = p0;
            out[E + e0] = w0;
        }
    }
}

// ---------------------------------------------------------------------------
// Fallbacks (only if d_ws can't hold the f16 z copy)
// ---------------------------------------------------------------------------
__global__ __launch_bounds__(256) void precompute_scalar(
    const float* __restrict__ z, const float* __restrict__ W1,
    const float* __restrict__ b1,
    float* __restrict__ U, float* __restrict__ V, int n_nodes)
{
    const int node = blockIdx.x * 256 + threadIdx.x;
    if (node >= n_nodes) return;
    const float4* zp = (const float4*)(z + (size_t)node * NODE_D);
    float u[HID], v[HID];
    #pragma unroll
    for (int j = 0; j < HID; ++j) { u[j] = b1[j]; v[j] = 0.f; }
    #pragma unroll 1
    for (int c = 0; c < NODE_D / 4; ++c) {
        float4 za = zp[c];
        const float* wu = W1 + (size_t)c * 4 * HID;
        const float* wv = wu + NODE_D * HID;
        #pragma unroll
        for (int j = 0; j < HID; ++j) {
            u[j] = fmaf(za.x, wu[j], fmaf(za.y, wu[HID + j],
                   fmaf(za.z, wu[2 * HID + j], fmaf(za.w, wu[3 * HID + j], u[j]))));
            v[j] = fmaf(za.x, wv[j], fmaf(za.y, wv[HID + j],
                   fmaf(za.z, wv[2 * HID + j], fmaf(za.w, wv[3 * HID + j], v[j]))));
        }
    }
    float4* up = (float4*)(U + (size_t)node * HID);
    float4* vp = (float4*)(V + (size_t)node * HID);
    #pragma unroll
    for (int q = 0; q < 4; ++q) {
        up[q] = make_float4(u[4*q], u[4*q+1], u[4*q+2], u[4*q+3]);
        vp[q] = make_float4(v[4*q], v[4*q+1], v[4*q+2], v[4*q+3]);
    }
}

__global__ __launch_bounds__(256) void edge_kernel_f32(
    const float* __restrict__ z, const int* __restrict__ ei,
    const float* __restrict__ U, const float* __restrict__ V,
    const float* __restrict__ W2, const float* __restrict__ b2,
    float* __restrict__ out, int E)
{
    const int gid  = blockIdx.x * blockDim.x + threadIdx.x;
    const int eid  = gid >> 4;
    const int lane = threadIdx.x & 15;
    if (eid >= E) return;
    const int row = ei[eid];
    const int col = ei[E + eid];
    const float4* zr = (const float4*)(z + (size_t)row * NODE_D);
    const float4* zc = (const float4*)(z + (size_t)col * NODE_D);
    float4 a0 = zr[lane], a1 = zr[lane + 16];
    float4 c0 = zc[lane], c1 = zc[lane + 16];
    float p = a0.x*c0.x + a0.y*c0.y + a0.z*c0.z + a0.w*c0.w
            + a1.x*c1.x + a1.y*c1.y + a1.z*c1.z + a1.w*c1.w;
    p += __shfl_xor(p, 1); p += __shfl_xor(p, 2);
    p += __shfl_xor(p, 4); p += __shfl_xor(p, 8);
    float t = fmaxf(U[(size_t)row * HID + lane] + V[(size_t)col * HID + lane], 0.f) * W2[lane];
    t += __shfl_xor(t, 1); t += __shfl_xor(t, 2);
    t += __shfl_xor(t, 4); t += __shfl_xor(t, 8);
    if (lane == 0) {
        float x = t + b2[0];
        out[eid]     = p;
        out[E + eid] = fmaxf(x, 0.f) + log1pf(expf(-fabsf(x)));
    }
}

extern "C" void kernel_launch(void* const* d_in, const int* in_sizes, int n_in,
                              void* d_out, int out_size, void* d_ws, size_t ws_size,
                              hipStream_t stream) {
    const float* z  = (const float*)d_in[0];
    const int*   ei = (const int*)  d_in[1];
    const float* W1 = (const float*)d_in[2];
    const float* b1 = (const float*)d_in[3];
    const float* W2 = (const float*)d_in[4];
    const float* b2 = (const float*)d_in[5];
    float* out = (float*)d_out;

    const int n_nodes = in_sizes[0] / NODE_D;   // 100000
    const int E       = in_sizes[1] / 2;        // 600000

    const size_t needUV = (size_t)2 * n_nodes * HID * sizeof(float);  // 12.8 MB
    const size_t needZh = (size_t)n_nodes * NODE_D * 2;               // 25.6 MB
    const int use_f16   = (ws_size >= needUV + needZh);

    float* U  = (float*)d_ws;
    float* V  = U + (size_t)n_nodes * HID;
    uint4* zh = (uint4*)((char*)d_ws + needUV);

    if (use_f16) {
        precompute_mfma<<<(n_nodes + 63) / 64, 256, 0, stream>>>(
            z, W1, b1, U, V, zh, n_nodes);
        const long long groups  = ((long long)E + 1) / 2;
        const long long threads = groups * 16;
        edge_kernel_f16<<<(unsigned)((threads + 255) / 256), 256, 0, stream>>>(
            zh, ei, U, V, W2, b2, out, E);
    } else {
        precompute_scalar<<<(n_nodes + 255) / 256, 256, 0, stream>>>(
            z, W1, b1, U, V, n_nodes);
        const long long threads = (long long)E * 16;
        edge_kernel_f32<<<(unsigned)((threads + 255) / 256), 256, 0, stream>>>(
            z, ei, U, V, W2, b2, out, E);
    }
}

// Round 6
// 164.242 us; speedup vs baseline: 1.3610x; 1.0042x over previous
//
#include <hip/hip_runtime.h>
#include <math.h>

#define NODE_D 128
#define HID 16
#define RECB 320   // per-node record: [z f16 256B][U f16 32B][V f16 32B], 5 cache lines

typedef _Float16 f16x8_t __attribute__((ext_vector_type(8)));
typedef _Float16 f16x2_t __attribute__((ext_vector_type(2)));
typedef float    f32x4_t __attribute__((ext_vector_type(4)));

// ---------------------------------------------------------------------------
// Kernel 1 (MFMA f16): builds the 320B node records.
//   rec[n] = { f16(z[n]) , U[n]=f16(z@W1[:128]+b1) , V[n]=f16(z@W1[128:]) }
// W1 staged once per block into LDS in fragment order; one wave = 16 nodes.
// ---------------------------------------------------------------------------
__global__ __launch_bounds__(256) void precompute_mfma(
    const float* __restrict__ z, const float* __restrict__ W1,
    const float* __restrict__ b1,
    unsigned char* __restrict__ rec, int n_nodes)
{
    // fragment-ordered W1: lds[((s*4+q)*16 + m)*8 + jj] = W1[(32s+8q+jj)*16 + m]
    __shared__ _Float16 ldsU[4096];   // 8 KB
    __shared__ _Float16 ldsV[4096];   // 8 KB

    const int tid = threadIdx.x;
    #pragma unroll
    for (int i = 0; i < 32; ++i) {
        const int e = i * 256 + tid;          // coalesced over W1's 8192 floats
        const float val = W1[e];
        int k = e >> 4;
        const int m = e & 15;
        _Float16* dst = ldsU;
        if (k >= NODE_D) { k -= NODE_D; dst = ldsV; }
        const int s = k >> 5, q = (k >> 3) & 3, jj = k & 7;
        dst[(((s * 4 + q) * 16 + m) << 3) + jj] = (_Float16)val;
    }
    __syncthreads();

    const int wave  = tid >> 6;
    const int lane  = tid & 63;
    const int m     = lane & 15;
    const int quad  = lane >> 4;
    const int nbase = blockIdx.x * 64 + wave * 16;
    const int node  = nbase + m;
    const int nodec = node < n_nodes ? node : (n_nodes - 1);

    // ---- A fragments from z (+ write f16 z into the record) ----
    f16x8_t a[4];
    const float4* zrow = (const float4*)(z + (size_t)nodec * NODE_D);
    unsigned char* myrec = rec + (size_t)node * RECB;
    #pragma unroll
    for (int s = 0; s < 4; ++s) {
        float4 f0 = zrow[s * 8 + quad * 2];
        float4 f1 = zrow[s * 8 + quad * 2 + 1];
        union { f16x8_t v; _Float16 h[8]; uint4 q4; } ta;
        ta.h[0] = (_Float16)f0.x; ta.h[1] = (_Float16)f0.y;
        ta.h[2] = (_Float16)f0.z; ta.h[3] = (_Float16)f0.w;
        ta.h[4] = (_Float16)f1.x; ta.h[5] = (_Float16)f1.y;
        ta.h[6] = (_Float16)f1.z; ta.h[7] = (_Float16)f1.w;
        a[s] = ta.v;
        if (node < n_nodes)
            *(uint4*)(myrec + ((s * 4 + quad) << 4)) = ta.q4;
    }

    // ---- B fragments from LDS, MFMA (b1 folded into U accumulator) ----
    const float bias = b1[m];
    f32x4_t accU = {bias, bias, bias, bias};
    f32x4_t accV = {0.f, 0.f, 0.f, 0.f};
    #pragma unroll
    for (int s = 0; s < 4; ++s) {
        f16x8_t bu = *(const f16x8_t*)(ldsU + (((s * 4 + quad) * 16 + m) << 3));
        f16x8_t bv = *(const f16x8_t*)(ldsV + (((s * 4 + quad) * 16 + m) << 3));
        accU = __builtin_amdgcn_mfma_f32_16x16x32_f16(a[s], bu, accU, 0, 0, 0);
        accV = __builtin_amdgcn_mfma_f32_16x16x32_f16(a[s], bv, accV, 0, 0, 0);
    }

    // ---- store U/V as f16 into the record's 5th cache line ----
    // lane holds D[row=quad*4+r][col=m]; 16 lanes of a quad write 32B segment
    #pragma unroll
    for (int r = 0; r < 4; ++r) {
        const int nodeo = nbase + quad * 4 + r;
        if (nodeo < n_nodes) {
            unsigned char* orec = rec + (size_t)nodeo * RECB;
            *(_Float16*)(orec + 256 + 2 * m) = (_Float16)accU[r];
            *(_Float16*)(orec + 288 + 2 * m) = (_Float16)accV[r];
        }
    }
}

// dot of 8 packed f16 pairs via v_dot2_f32_f16
__device__ __forceinline__ float dot_f16x8(uint4 a, uint4 c) {
    union { uint4 u; f16x2_t h[4]; } A, C;
    A.u = a; C.u = c;
    float p = 0.f;
#if __has_builtin(__builtin_amdgcn_fdot2)
    #pragma unroll
    for (int q = 0; q < 4; ++q)
        p = __builtin_amdgcn_fdot2(A.h[q], C.h[q], p, false);
#else
    #pragma unroll
    for (int q = 0; q < 4; ++q) {
        p = fmaf((float)A.h[q][0], (float)C.h[q][0], p);
        p = fmaf((float)A.h[q][1], (float)C.h[q][1], p);
    }
#endif
    return p;
}

__device__ __forceinline__ float softplus_f(float x) {
    return fmaxf(x, 0.f) + log1pf(expf(-fabsf(x)));
}

// ---------------------------------------------------------------------------
// Kernel 2: 16 lanes handle FOUR edges -> 8 zh uint4 gathers + 8 f16 U/V
// loads in flight per thread (2x R5's ILP; the edge pass is gather-latency
// bound — R3->R4's identical doubling gave 116->61 us).
// ---------------------------------------------------------------------------
__global__ __launch_bounds__(256) void edge_kernel_f16(
    const unsigned char* __restrict__ rec, const int* __restrict__ ei,
    const float* __restrict__ W2, const float* __restrict__ b2,
    float* __restrict__ out, int E)
{
    const int gid  = blockIdx.x * 256 + threadIdx.x;
    const int g    = gid >> 4;          // edge-quad id
    const int lane = threadIdx.x & 15;
    const int e0   = 4 * g;
    if (e0 >= E) return;
    const bool full = (e0 + 3) < E;

    int4 rr, cc;
    if (full) {
        rr = *(const int4*)(ei + e0);
        cc = *(const int4*)(ei + E + e0);
    } else {
        const int i1 = min(e0 + 1, E - 1), i2 = min(e0 + 2, E - 1), i3 = min(e0 + 3, E - 1);
        rr = make_int4(ei[e0], ei[i1], ei[i2], ei[i3]);
        cc = make_int4(ei[E + e0], ei[E + i1], ei[E + i2], ei[E + i3]);
    }

    const unsigned char* R0 = rec + (size_t)rr.x * RECB;
    const unsigned char* R1 = rec + (size_t)rr.y * RECB;
    const unsigned char* R2 = rec + (size_t)rr.z * RECB;
    const unsigned char* R3 = rec + (size_t)rr.w * RECB;
    const unsigned char* C0 = rec + (size_t)cc.x * RECB;
    const unsigned char* C1 = rec + (size_t)cc.y * RECB;
    const unsigned char* C2 = rec + (size_t)cc.z * RECB;
    const unsigned char* C3 = rec + (size_t)cc.w * RECB;

    const int zo = lane << 4;     // 16 B per lane within the 256 B z block
    uint4 za0 = *(const uint4*)(R0 + zo);
    uint4 zc0 = *(const uint4*)(C0 + zo);
    uint4 za1 = *(const uint4*)(R1 + zo);
    uint4 zc1 = *(const uint4*)(C1 + zo);
    uint4 za2 = *(const uint4*)(R2 + zo);
    uint4 zc2 = *(const uint4*)(C2 + zo);
    uint4 za3 = *(const uint4*)(R3 + zo);
    uint4 zc3 = *(const uint4*)(C3 + zo);

    const int uo = 256 + 2 * lane;   // U f16 at +256, V f16 at +288
    const int vo = 288 + 2 * lane;
    float u0 = (float)*(const _Float16*)(R0 + uo);
    float v0 = (float)*(const _Float16*)(C0 + vo);
    float u1 = (float)*(const _Float16*)(R1 + uo);
    float v1 = (float)*(const _Float16*)(C1 + vo);
    float u2 = (float)*(const _Float16*)(R2 + uo);
    float v2 = (float)*(const _Float16*)(C2 + vo);
    float u3 = (float)*(const _Float16*)(R3 + uo);
    float v3 = (float)*(const _Float16*)(C3 + vo);
    float w2 = W2[lane];

    float p0 = dot_f16x8(za0, zc0);
    float p1 = dot_f16x8(za1, zc1);
    float p2 = dot_f16x8(za2, zc2);
    float p3 = dot_f16x8(za3, zc3);
    #pragma unroll
    for (int s = 1; s < 16; s <<= 1) {
        p0 += __shfl_xor(p0, s);
        p1 += __shfl_xor(p1, s);
        p2 += __shfl_xor(p2, s);
        p3 += __shfl_xor(p3, s);
    }

    float t0 = fmaxf(u0 + v0, 0.f) * w2;   // b1 already folded into U
    float t1 = fmaxf(u1 + v1, 0.f) * w2;
    float t2 = fmaxf(u2 + v2, 0.f) * w2;
    float t3 = fmaxf(u3 + v3, 0.f) * w2;
    #pragma unroll
    for (int s = 1; s < 16; s <<= 1) {
        t0 += __shfl_xor(t0, s);
        t1 += __shfl_xor(t1, s);
        t2 += __shfl_xor(t2, s);
        t3 += __shfl_xor(t3, s);
    }

    if (lane == 0) {
        const float bb = b2[0];
        float w0 = softplus_f(t0 + bb);
        float w1 = softplus_f(t1 + bb);
        float w2s = softplus_f(t2 + bb);
        float w3 = softplus_f(t3 + bb);
        if (full) {   // e0 % 4 == 0 and E % 4 == 0 -> 16 B aligned
            *(float4*)(out + e0)     = make_float4(p0, p1, p2, p3);
            *(float4*)(out + E + e0) = make_float4(w0, w1, w2s, w3);
        } else {
            const float pv[4] = {p0, p1, p2, p3};
            const float wv[4] = {w0, w1, w2s, w3};
            for (int j = 0; j < 4 && e0 + j < E; ++j) {
                out[e0 + j]     = pv[j];
                out[E + e0 + j] = wv[j];
            }
        }
    }
}

// ---------------------------------------------------------------------------
// Fallbacks (only if d_ws can't hold the 32 MB record array)
// ---------------------------------------------------------------------------
__global__ __launch_bounds__(256) void precompute_scalar(
    const float* __restrict__ z, const float* __restrict__ W1,
    const float* __restrict__ b1,
    float* __restrict__ U, float* __restrict__ V, int n_nodes)
{
    const int node = blockIdx.x * 256 + threadIdx.x;
    if (node >= n_nodes) return;
    const float4* zp = (const float4*)(z + (size_t)node * NODE_D);
    float u[HID], v[HID];
    #pragma unroll
    for (int j = 0; j < HID; ++j) { u[j] = b1[j]; v[j] = 0.f; }
    #pragma unroll 1
    for (int c = 0; c < NODE_D / 4; ++c) {
        float4 za = zp[c];
        const float* wu = W1 + (size_t)c * 4 * HID;
        const float* wv = wu + NODE_D * HID;
        #pragma unroll
        for (int j = 0; j < HID; ++j) {
            u[j] = fmaf(za.x, wu[j], fmaf(za.y, wu[HID + j],
                   fmaf(za.z, wu[2 * HID + j], fmaf(za.w, wu[3 * HID + j], u[j]))));
            v[j] = fmaf(za.x, wv[j], fmaf(za.y, wv[HID + j],
                   fmaf(za.z, wv[2 * HID + j], fmaf(za.w, wv[3 * HID + j], v[j]))));
        }
    }
    float4* up = (float4*)(U + (size_t)node * HID);
    float4* vp = (float4*)(V + (size_t)node * HID);
    #pragma unroll
    for (int q = 0; q < 4; ++q) {
        up[q] = make_float4(u[4*q], u[4*q+1], u[4*q+2], u[4*q+3]);
        vp[q] = make_float4(v[4*q], v[4*q+1], v[4*q+2], v[4*q+3]);
    }
}

__global__ __launch_bounds__(256) void edge_kernel_f32(
    const float* __restrict__ z, const int* __restrict__ ei,
    const float* __restrict__ U, const float* __restrict__ V,
    const float* __restrict__ W2, const float* __restrict__ b2,
    float* __restrict__ out, int E)
{
    const int gid  = blockIdx.x * blockDim.x + threadIdx.x;
    const int eid  = gid >> 4;
    const int lane = threadIdx.x & 15;
    if (eid >= E) return;
    const int row = ei[eid];
    const int col = ei[E + eid];
    const float4* zr = (const float4*)(z + (size_t)row * NODE_D);
    const float4* zc = (const float4*)(z + (size_t)col * NODE_D);
    float4 a0 = zr[lane], a1 = zr[lane + 16];
    float4 c0 = zc[lane], c1 = zc[lane + 16];
    float p = a0.x*c0.x + a0.y*c0.y + a0.z*c0.z + a0.w*c0.w
            + a1.x*c1.x + a1.y*c1.y + a1.z*c1.z + a1.w*c1.w;
    p += __shfl_xor(p, 1); p += __shfl_xor(p, 2);
    p += __shfl_xor(p, 4); p += __shfl_xor(p, 8);
    float t = fmaxf(U[(size_t)row * HID + lane] + V[(size_t)col * HID + lane], 0.f) * W2[lane];
    t += __shfl_xor(t, 1); t += __shfl_xor(t, 2);
    t += __shfl_xor(t, 4); t += __shfl_xor(t, 8);
    if (lane == 0) {
        float x = t + b2[0];
        out[eid]     = p;
        out[E + eid] = softplus_f(x);
    }
}

extern "C" void kernel_launch(void* const* d_in, const int* in_sizes, int n_in,
                              void* d_out, int out_size, void* d_ws, size_t ws_size,
                              hipStream_t stream) {
    const float* z  = (const float*)d_in[0];
    const int*   ei = (const int*)  d_in[1];
    const float* W1 = (const float*)d_in[2];
    const float* b1 = (const float*)d_in[3];
    const float* W2 = (const float*)d_in[4];
    const float* b2 = (const float*)d_in[5];
    float* out = (float*)d_out;

    const int n_nodes = in_sizes[0] / NODE_D;   // 100000
    const int E       = in_sizes[1] / 2;        // 600000

    const size_t needRec = (size_t)n_nodes * RECB;   // 32 MB
    const int use_f16    = (ws_size >= needRec);

    if (use_f16) {
        unsigned char* rec = (unsigned char*)d_ws;
        precompute_mfma<<<(n_nodes + 63) / 64, 256, 0, stream>>>(
            z, W1, b1, rec, n_nodes);
        const long long groups  = ((long long)E + 3) / 4;
        const long long threads = groups * 16;
        edge_kernel_f16<<<(unsigned)((threads + 255) / 256), 256, 0, stream>>>(
            rec, ei, W2, b2, out, E);
    } else {
        float* U = (float*)d_ws;
        float* V = U + (size_t)n_nodes * HID;
        precompute_scalar<<<(n_nodes + 255) / 256, 256, 0, stream>>>(
            z, W1, b1, U, V, n_nodes);
        const long long threads = (long long)E * 16;
        edge_kernel_f32<<<(unsigned)((threads + 255) / 256), 256, 0, stream>>>(
            z, ei, U, V, W2, b2, out, E);
    }
}

// Round 7
// 147.684 us; speedup vs baseline: 1.5136x; 1.1121x over previous
//
#include <hip/hip_runtime.h>
#include <math.h>

#define NODE_D 128
#define HID 16

#if __has_builtin(__builtin_amdgcn_cvt_pk_f32_fp8) && __has_builtin(__builtin_amdgcn_cvt_pk_fp8_f32)
#define USE_FP8 1
#define RECB 192   // [z fp8 128B][U f16 32B][V f16 32B] -> 3 cache lines
#define UOFF 128
#define VOFF 160
#else
#define USE_FP8 0
#define RECB 320   // [z f16 256B][U f16 32B][V f16 32B] -> 5 cache lines
#define UOFF 256
#define VOFF 288
#endif

typedef _Float16 f16x8_t __attribute__((ext_vector_type(8)));
typedef _Float16 f16x2_t __attribute__((ext_vector_type(2)));
typedef float    f32x4_t __attribute__((ext_vector_type(4)));
typedef float    f32x2_t __attribute__((ext_vector_type(2)));

// ---------------------------------------------------------------------------
// Kernel 1 (MFMA f16): builds node records.
//   rec[n] = { z[n] (fp8 or f16) , U[n]=f16(z@W1[:128]+b1) , V[n]=f16(z@W1[128:]) }
// W1 staged once per block into LDS in fragment order; one wave = 16 nodes.
// A layout: A[m=lane&15][k=quad*8+j (+32s)]; C/D: col=lane&15, row=quad*4+reg.
// ---------------------------------------------------------------------------
__global__ __launch_bounds__(256) void precompute_mfma(
    const float* __restrict__ z, const float* __restrict__ W1,
    const float* __restrict__ b1,
    unsigned char* __restrict__ rec, int n_nodes)
{
    __shared__ _Float16 ldsU[4096];   // 8 KB, fragment-ordered W1 rows 0..127
    __shared__ _Float16 ldsV[4096];   // 8 KB, rows 128..255

    const int tid = threadIdx.x;
    #pragma unroll
    for (int i = 0; i < 32; ++i) {
        const int e = i * 256 + tid;          // coalesced over W1's 8192 floats
        const float val = W1[e];
        int k = e >> 4;
        const int m = e & 15;
        _Float16* dst = ldsU;
        if (k >= NODE_D) { k -= NODE_D; dst = ldsV; }
        const int s = k >> 5, q = (k >> 3) & 3, jj = k & 7;
        dst[(((s * 4 + q) * 16 + m) << 3) + jj] = (_Float16)val;
    }
    __syncthreads();

    const int wave  = tid >> 6;
    const int lane  = tid & 63;
    const int m     = lane & 15;
    const int quad  = lane >> 4;
    const int nbase = blockIdx.x * 64 + wave * 16;
    const int node  = nbase + m;
    const int nodec = node < n_nodes ? node : (n_nodes - 1);

    // ---- A fragments from z (+ write compressed z into the record) ----
    f16x8_t a[4];
    const float4* zrow = (const float4*)(z + (size_t)nodec * NODE_D);
    unsigned char* myrec = rec + (size_t)node * RECB;
    #pragma unroll
    for (int s = 0; s < 4; ++s) {
        float4 f0 = zrow[s * 8 + quad * 2];
        float4 f1 = zrow[s * 8 + quad * 2 + 1];
        union { f16x8_t v; _Float16 h[8]; uint4 q4; } ta;
        ta.h[0] = (_Float16)f0.x; ta.h[1] = (_Float16)f0.y;
        ta.h[2] = (_Float16)f0.z; ta.h[3] = (_Float16)f0.w;
        ta.h[4] = (_Float16)f1.x; ta.h[5] = (_Float16)f1.y;
        ta.h[6] = (_Float16)f1.z; ta.h[7] = (_Float16)f1.w;
        a[s] = ta.v;
        if (node < n_nodes) {
#if USE_FP8
            // pack 8 floats -> 8 fp8 e4m3 (RNE), dims s*32+quad*8 .. +7
            int w0 = __builtin_amdgcn_cvt_pk_fp8_f32(f0.x, f0.y, 0, false);
            w0     = __builtin_amdgcn_cvt_pk_fp8_f32(f0.z, f0.w, w0, true);
            int w1 = __builtin_amdgcn_cvt_pk_fp8_f32(f1.x, f1.y, 0, false);
            w1     = __builtin_amdgcn_cvt_pk_fp8_f32(f1.z, f1.w, w1, true);
            *(uint2*)(myrec + ((s * 4 + quad) << 3)) = make_uint2((unsigned)w0, (unsigned)w1);
#else
            *(uint4*)(myrec + ((s * 4 + quad) << 4)) = ta.q4;
#endif
        }
    }

    // ---- B fragments from LDS, MFMA (b1 folded into U accumulator) ----
    const float bias = b1[m];
    f32x4_t accU = {bias, bias, bias, bias};
    f32x4_t accV = {0.f, 0.f, 0.f, 0.f};
    #pragma unroll
    for (int s = 0; s < 4; ++s) {
        f16x8_t bu = *(const f16x8_t*)(ldsU + (((s * 4 + quad) * 16 + m) << 3));
        f16x8_t bv = *(const f16x8_t*)(ldsV + (((s * 4 + quad) * 16 + m) << 3));
        accU = __builtin_amdgcn_mfma_f32_16x16x32_f16(a[s], bu, accU, 0, 0, 0);
        accV = __builtin_amdgcn_mfma_f32_16x16x32_f16(a[s], bv, accV, 0, 0, 0);
    }

    // ---- store U/V f16 into the record ----
    #pragma unroll
    for (int r = 0; r < 4; ++r) {
        const int nodeo = nbase + quad * 4 + r;
        if (nodeo < n_nodes) {
            unsigned char* orec = rec + (size_t)nodeo * RECB;
            *(_Float16*)(orec + UOFF + 2 * m) = (_Float16)accU[r];
            *(_Float16*)(orec + VOFF + 2 * m) = (_Float16)accV[r];
        }
    }
}

__device__ __forceinline__ float softplus_f(float x) {
    return fmaxf(x, 0.f) + log1pf(expf(-fabsf(x)));
}

#if USE_FP8
// dot of 16 fp8 pairs (one uint4 each side)
__device__ __forceinline__ float dot_fp8x16(uint4 a, uint4 c) {
    const unsigned* au = (const unsigned*)&a;
    const unsigned* cu = (const unsigned*)&c;
    float p = 0.f;
    #pragma unroll
    for (int q = 0; q < 4; ++q) {
        f32x2_t alo = __builtin_amdgcn_cvt_pk_f32_fp8(au[q], false);
        f32x2_t clo = __builtin_amdgcn_cvt_pk_f32_fp8(cu[q], false);
        f32x2_t ahi = __builtin_amdgcn_cvt_pk_f32_fp8(au[q], true);
        f32x2_t chi = __builtin_amdgcn_cvt_pk_f32_fp8(cu[q], true);
        p = fmaf(alo.x, clo.x, p);
        p = fmaf(alo.y, clo.y, p);
        p = fmaf(ahi.x, chi.x, p);
        p = fmaf(ahi.y, chi.y, p);
    }
    return p;
}

// ---------------------------------------------------------------------------
// Kernel 2 (fp8 records): 8 lanes per edge, 4 edges per group.
// Per thread: 8 z uint4 gathers (16 B/lane covers the 128 B fp8 z block)
// + 8 f16x2 U/V loads in flight. 3-stage reduction.
// ---------------------------------------------------------------------------
__global__ __launch_bounds__(256) void edge_kernel_rec(
    const unsigned char* __restrict__ rec, const int* __restrict__ ei,
    const float* __restrict__ W2, const float* __restrict__ b2,
    float* __restrict__ out, int E)
{
    const int gid  = blockIdx.x * 256 + threadIdx.x;
    const int g    = gid >> 3;          // edge-quad id
    const int lane = threadIdx.x & 7;
    const int e0   = 4 * g;
    if (e0 >= E) return;
    const bool full = (e0 + 3) < E;

    int4 rr, cc;
    if (full) {
        rr = *(const int4*)(ei + e0);
        cc = *(const int4*)(ei + E + e0);
    } else {
        const int i1 = min(e0 + 1, E - 1), i2 = min(e0 + 2, E - 1), i3 = min(e0 + 3, E - 1);
        rr = make_int4(ei[e0], ei[i1], ei[i2], ei[i3]);
        cc = make_int4(ei[E + e0], ei[E + i1], ei[E + i2], ei[E + i3]);
    }

    const unsigned char* R0 = rec + (size_t)rr.x * RECB;
    const unsigned char* R1 = rec + (size_t)rr.y * RECB;
    const unsigned char* R2 = rec + (size_t)rr.z * RECB;
    const unsigned char* R3 = rec + (size_t)rr.w * RECB;
    const unsigned char* C0 = rec + (size_t)cc.x * RECB;
    const unsigned char* C1 = rec + (size_t)cc.y * RECB;
    const unsigned char* C2 = rec + (size_t)cc.z * RECB;
    const unsigned char* C3 = rec + (size_t)cc.w * RECB;

    const int zo = lane << 4;     // 16 B per lane within the 128 B fp8 z block
    uint4 za0 = *(const uint4*)(R0 + zo);
    uint4 zc0 = *(const uint4*)(C0 + zo);
    uint4 za1 = *(const uint4*)(R1 + zo);
    uint4 zc1 = *(const uint4*)(C1 + zo);
    uint4 za2 = *(const uint4*)(R2 + zo);
    uint4 zc2 = *(const uint4*)(C2 + zo);
    uint4 za3 = *(const uint4*)(R3 + zo);
    uint4 zc3 = *(const uint4*)(C3 + zo);

    const int uo = UOFF + (lane << 2);   // lane handles hidden units 2l, 2l+1
    const int vo = VOFF + (lane << 2);
    f16x2_t u0 = *(const f16x2_t*)(R0 + uo);
    f16x2_t v0 = *(const f16x2_t*)(C0 + vo);
    f16x2_t u1 = *(const f16x2_t*)(R1 + uo);
    f16x2_t v1 = *(const f16x2_t*)(C1 + vo);
    f16x2_t u2 = *(const f16x2_t*)(R2 + uo);
    f16x2_t v2 = *(const f16x2_t*)(C2 + vo);
    f16x2_t u3 = *(const f16x2_t*)(R3 + uo);
    f16x2_t v3 = *(const f16x2_t*)(C3 + vo);
    const float2 w2 = ((const float2*)W2)[lane];

    float p0 = dot_fp8x16(za0, zc0);
    float p1 = dot_fp8x16(za1, zc1);
    float p2 = dot_fp8x16(za2, zc2);
    float p3 = dot_fp8x16(za3, zc3);
    #pragma unroll
    for (int s = 1; s < 8; s <<= 1) {
        p0 += __shfl_xor(p0, s);
        p1 += __shfl_xor(p1, s);
        p2 += __shfl_xor(p2, s);
        p3 += __shfl_xor(p3, s);
    }

    float t0 = fmaxf((float)u0.x + (float)v0.x, 0.f) * w2.x
             + fmaxf((float)u0.y + (float)v0.y, 0.f) * w2.y;
    float t1 = fmaxf((float)u1.x + (float)v1.x, 0.f) * w2.x
             + fmaxf((float)u1.y + (float)v1.y, 0.f) * w2.y;
    float t2 = fmaxf((float)u2.x + (float)v2.x, 0.f) * w2.x
             + fmaxf((float)u2.y + (float)v2.y, 0.f) * w2.y;
    float t3 = fmaxf((float)u3.x + (float)v3.x, 0.f) * w2.x
             + fmaxf((float)u3.y + (float)v3.y, 0.f) * w2.y;
    #pragma unroll
    for (int s = 1; s < 8; s <<= 1) {
        t0 += __shfl_xor(t0, s);
        t1 += __shfl_xor(t1, s);
        t2 += __shfl_xor(t2, s);
        t3 += __shfl_xor(t3, s);
    }

    if (lane == 0) {
        const float bb = b2[0];
        float w0 = softplus_f(t0 + bb);
        float w1 = softplus_f(t1 + bb);
        float ws = softplus_f(t2 + bb);
        float w3 = softplus_f(t3 + bb);
        if (full) {   // e0 % 4 == 0 and E % 4 == 0 -> 16 B aligned
            *(float4*)(out + e0)     = make_float4(p0, p1, p2, p3);
            *(float4*)(out + E + e0) = make_float4(w0, w1, ws, w3);
        } else {
            const float pv[4] = {p0, p1, p2, p3};
            const float wv[4] = {w0, w1, ws, w3};
            for (int j = 0; j < 4 && e0 + j < E; ++j) {
                out[e0 + j]     = pv[j];
                out[E + e0 + j] = wv[j];
            }
        }
    }
}

#else  // !USE_FP8 — f16 records, 16 lanes per edge, 4 edges per group (R6 path)

__device__ __forceinline__ float dot_f16x8(uint4 a, uint4 c) {
    union { uint4 u; f16x2_t h[4]; } A, C;
    A.u = a; C.u = c;
    float p = 0.f;
#if __has_builtin(__builtin_amdgcn_fdot2)
    #pragma unroll
    for (int q = 0; q < 4; ++q)
        p = __builtin_amdgcn_fdot2(A.h[q], C.h[q], p, false);
#else
    #pragma unroll
    for (int q = 0; q < 4; ++q) {
        p = fmaf((float)A.h[q][0], (float)C.h[q][0], p);
        p = fmaf((float)A.h[q][1], (float)C.h[q][1], p);
    }
#endif
    return p;
}

__global__ __launch_bounds__(256) void edge_kernel_rec(
    const unsigned char* __restrict__ rec, const int* __restrict__ ei,
    const float* __restrict__ W2, const float* __restrict__ b2,
    float* __restrict__ out, int E)
{
    const int gid  = blockIdx.x * 256 + threadIdx.x;
    const int g    = gid >> 4;
    const int lane = threadIdx.x & 15;
    const int e0   = 4 * g;
    if (e0 >= E) return;
    const bool full = (e0 + 3) < E;

    int4 rr, cc;
    if (full) {
        rr = *(const int4*)(ei + e0);
        cc = *(const int4*)(ei + E + e0);
    } else {
        const int i1 = min(e0 + 1, E - 1), i2 = min(e0 + 2, E - 1), i3 = min(e0 + 3, E - 1);
        rr = make_int4(ei[e0], ei[i1], ei[i2], ei[i3]);
        cc = make_int4(ei[E + e0], ei[E + i1], ei[E + i2], ei[E + i3]);
    }

    const unsigned char* R0 = rec + (size_t)rr.x * RECB;
    const unsigned char* R1 = rec + (size_t)rr.y * RECB;
    const unsigned char* R2 = rec + (size_t)rr.z * RECB;
    const unsigned char* R3 = rec + (size_t)rr.w * RECB;
    const unsigned char* C0 = rec + (size_t)cc.x * RECB;
    const unsigned char* C1 = rec + (size_t)cc.y * RECB;
    const unsigned char* C2 = rec + (size_t)cc.z * RECB;
    const unsigned char* C3 = rec + (size_t)cc.w * RECB;

    const int zo = lane << 4;
    uint4 za0 = *(const uint4*)(R0 + zo);
    uint4 zc0 = *(const uint4*)(C0 + zo);
    uint4 za1 = *(const uint4*)(R1 + zo);
    uint4 zc1 = *(const uint4*)(C1 + zo);
    uint4 za2 = *(const uint4*)(R2 + zo);
    uint4 zc2 = *(const uint4*)(C2 + zo);
    uint4 za3 = *(const uint4*)(R3 + zo);
    uint4 zc3 = *(const uint4*)(C3 + zo);

    const int uo = UOFF + 2 * lane;
    const int vo = VOFF + 2 * lane;
    float u0 = (float)*(const _Float16*)(R0 + uo);
    float v0 = (float)*(const _Float16*)(C0 + vo);
    float u1 = (float)*(const _Float16*)(R1 + uo);
    float v1 = (float)*(const _Float16*)(C1 + vo);
    float u2 = (float)*(const _Float16*)(R2 + uo);
    float v2 = (float)*(const _Float16*)(C2 + vo);
    float u3 = (float)*(const _Float16*)(R3 + uo);
    float v3 = (float)*(const _Float16*)(C3 + vo);
    float w2 = W2[lane];

    float p0 = dot_f16x8(za0, zc0);
    float p1 = dot_f16x8(za1, zc1);
    float p2 = dot_f16x8(za2, zc2);
    float p3 = dot_f16x8(za3, zc3);
    #pragma unroll
    for (int s = 1; s < 16; s <<= 1) {
        p0 += __shfl_xor(p0, s);
        p1 += __shfl_xor(p1, s);
        p2 += __shfl_xor(p2, s);
        p3 += __shfl_xor(p3, s);
    }

    float t0 = fmaxf(u0 + v0, 0.f) * w2;
    float t1 = fmaxf(u1 + v1, 0.f) * w2;
    float t2 = fmaxf(u2 + v2, 0.f) * w2;
    float t3 = fmaxf(u3 + v3, 0.f) * w2;
    #pragma unroll
    for (int s = 1; s < 16; s <<= 1) {
        t0 += __shfl_xor(t0, s);
        t1 += __shfl_xor(t1, s);
        t2 += __shfl_xor(t2, s);
        t3 += __shfl_xor(t3, s);
    }

    if (lane == 0) {
        const float bb = b2[0];
        float w0 = softplus_f(t0 + bb);
        float w1 = softplus_f(t1 + bb);
        float ws = softplus_f(t2 + bb);
        float w3 = softplus_f(t3 + bb);
        if (full) {
            *(float4*)(out + e0)     = make_float4(p0, p1, p2, p3);
            *(float4*)(out + E + e0) = make_float4(w0, w1, ws, w3);
        } else {
            const float pv[4] = {p0, p1, p2, p3};
            const float wv[4] = {w0, w1, ws, w3};
            for (int j = 0; j < 4 && e0 + j < E; ++j) {
                out[e0 + j]     = pv[j];
                out[E + e0 + j] = wv[j];
            }
        }
    }
}
#endif  // USE_FP8

// ---------------------------------------------------------------------------
// Fallbacks (only if d_ws can't hold the record array)
// ---------------------------------------------------------------------------
__global__ __launch_bounds__(256) void precompute_scalar(
    const float* __restrict__ z, const float* __restrict__ W1,
    const float* __restrict__ b1,
    float* __restrict__ U, float* __restrict__ V, int n_nodes)
{
    const int node = blockIdx.x * 256 + threadIdx.x;
    if (node >= n_nodes) return;
    const float4* zp = (const float4*)(z + (size_t)node * NODE_D);
    float u[HID], v[HID];
    #pragma unroll
    for (int j = 0; j < HID; ++j) { u[j] = b1[j]; v[j] = 0.f; }
    #pragma unroll 1
    for (int c = 0; c < NODE_D / 4; ++c) {
        float4 za = zp[c];
        const float* wu = W1 + (size_t)c * 4 * HID;
        const float* wv = wu + NODE_D * HID;
        #pragma unroll
        for (int j = 0; j < HID; ++j) {
            u[j] = fmaf(za.x, wu[j], fmaf(za.y, wu[HID + j],
                   fmaf(za.z, wu[2 * HID + j], fmaf(za.w, wu[3 * HID + j], u[j]))));
            v[j] = fmaf(za.x, wv[j], fmaf(za.y, wv[HID + j],
                   fmaf(za.z, wv[2 * HID + j], fmaf(za.w, wv[3 * HID + j], v[j]))));
        }
    }
    float4* up = (float4*)(U + (size_t)node * HID);
    float4* vp = (float4*)(V + (size_t)node * HID);
    #pragma unroll
    for (int q = 0; q < 4; ++q) {
        up[q] = make_float4(u[4*q], u[4*q+1], u[4*q+2], u[4*q+3]);
        vp[q] = make_float4(v[4*q], v[4*q+1], v[4*q+2], v[4*q+3]);
    }
}

__global__ __launch_bounds__(256) void edge_kernel_f32(
    const float* __restrict__ z, const int* __restrict__ ei,
    const float* __restrict__ U, const float* __restrict__ V,
    const float* __restrict__ W2, const float* __restrict__ b2,
    float* __restrict__ out, int E)
{
    const int gid  = blockIdx.x * blockDim.x + threadIdx.x;
    const int eid  = gid >> 4;
    const int lane = threadIdx.x & 15;
    if (eid >= E) return;
    const int row = ei[eid];
    const int col = ei[E + eid];
    const float4* zr = (const float4*)(z + (size_t)row * NODE_D);
    const float4* zc = (const float4*)(z + (size_t)col * NODE_D);
    float4 a0 = zr[lane], a1 = zr[lane + 16];
    float4 c0 = zc[lane], c1 = zc[lane + 16];
    float p = a0.x*c0.x + a0.y*c0.y + a0.z*c0.z + a0.w*c0.w
            + a1.x*c1.x + a1.y*c1.y + a1.z*c1.z + a1.w*c1.w;
    p += __shfl_xor(p, 1); p += __shfl_xor(p, 2);
    p += __shfl_xor(p, 4); p += __shfl_xor(p, 8);
    float t = fmaxf(U[(size_t)row * HID + lane] + V[(size_t)col * HID + lane], 0.f) * W2[lane];
    t += __shfl_xor(t, 1); t += __shfl_xor(t, 2);
    t += __shfl_xor(t, 4); t += __shfl_xor(t, 8);
    if (lane == 0) {
        float x = t + b2[0];
        out[eid]     = p;
        out[E + eid] = softplus_f(x);
    }
}

extern "C" void kernel_launch(void* const* d_in, const int* in_sizes, int n_in,
                              void* d_out, int out_size, void* d_ws, size_t ws_size,
                              hipStream_t stream) {
    const float* z  = (const float*)d_in[0];
    const int*   ei = (const int*)  d_in[1];
    const float* W1 = (const float*)d_in[2];
    const float* b1 = (const float*)d_in[3];
    const float* W2 = (const float*)d_in[4];
    const float* b2 = (const float*)d_in[5];
    float* out = (float*)d_out;

    const int n_nodes = in_sizes[0] / NODE_D;   // 100000
    const int E       = in_sizes[1] / 2;        // 600000

    const size_t needRec = (size_t)n_nodes * RECB;   // 19.2 MB (fp8) / 32 MB (f16)
    const int use_rec    = (ws_size >= needRec);

    if (use_rec) {
        unsigned char* rec = (unsigned char*)d_ws;
        precompute_mfma<<<(n_nodes + 63) / 64, 256, 0, stream>>>(
            z, W1, b1, rec, n_nodes);
        const long long groups  = ((long long)E + 3) / 4;
#if USE_FP8
        const long long threads = groups * 8;
#else
        const long long threads = groups * 16;
#endif
        edge_kernel_rec<<<(unsigned)((threads + 255) / 256), 256, 0, stream>>>(
            rec, ei, W2, b2, out, E);
    } else {
        float* U = (float*)d_ws;
        float* V = U + (size_t)n_nodes * HID;
        precompute_scalar<<<(n_nodes + 255) / 256, 256, 0, stream>>>(
            z, W1, b1, U, V, n_nodes);
        const long long threads = (long long)E * 16;
        edge_kernel_f32<<<(unsigned)((threads + 255) / 256), 256, 0, stream>>>(
            z, ei, U, V, W2, b2, out, E);
    }
}